// Round 1
// baseline (104726.404 us; speedup 1.0000x reference)
//
#include <hip/hip_runtime.h>
#include <hip/hip_bf16.h>

#define TSTEPS 512
#define BATCH  128
#define DIM    512
#define HDIM   512
#define ODIM   256
#define N3     1536   // 3*HDIM

// ws layout (float offsets):
//   sA: 0, sB: 65536, x: 131072, z: 163840, rs: 229376, ps: 294912, hv: 360448
#define OFF_SB 65536
#define OFF_X  131072
#define OFF_Z  163840
#define OFF_RS 229376
#define OFF_PS 294912
#define OFF_HV 360448

__device__ __forceinline__ float sigmoidf_(float a) {
  return 1.0f / (1.0f + __expf(-a));
}

// x0[b,j] = H[b,511,j] + H[b,511,j+256]; s0 = 0
__global__ void init_kernel(const float* __restrict__ H,
                            float* __restrict__ x,
                            float* __restrict__ sA) {
  int tid = blockIdx.x * 256 + threadIdx.x;   // 0..65535
  if (tid < BATCH * ODIM) {
    int b = tid >> 8;
    int j = tid & (ODIM - 1);
    const float* hrow = H + ((size_t)b * TSTEPS + (TSTEPS - 1)) * DIM;
    x[tid] = hrow[j] + hrow[j + ODIM];
  }
  sA[tid] = 0.0f;   // tid < BATCH*HDIM = 65536
}

// hv[i, j] = sum_d H[b, 511-l, d] * V[d, j],  i = l*128 + b, V = [V_r|V_z|V_s]
// tile 32 rows x 64 cols, 256 threads: c=tid&63 (col), q=tid>>6, rows q+4*rr
__global__ void hv_kernel(const float* __restrict__ H,
                          const float* __restrict__ Vr,
                          const float* __restrict__ Vz,
                          const float* __restrict__ Vs,
                          void* __restrict__ hv, int hv_bf16) {
  int c  = threadIdx.x & 63;
  int q  = threadIdx.x >> 6;
  int i0 = blockIdx.x * 32;
  int n0 = blockIdx.y * 64;
  int seg = n0 >> 9;
  int jj  = (n0 & 511) + c;
  const float* V = (seg == 0) ? Vr : ((seg == 1) ? Vz : Vs);

  const float* Arow[8];
  #pragma unroll
  for (int rr = 0; rr < 8; ++rr) {
    int i = i0 + q + rr * 4;
    int l = i >> 7;
    int b = i & 127;
    Arow[rr] = H + ((size_t)b * TSTEPS + (TSTEPS - 1 - l)) * DIM;
  }
  float acc[8];
  #pragma unroll
  for (int rr = 0; rr < 8; ++rr) acc[rr] = 0.0f;

  for (int k = 0; k < DIM; k += 4) {
    float b0 = V[(size_t)(k + 0) * HDIM + jj];
    float b1 = V[(size_t)(k + 1) * HDIM + jj];
    float b2 = V[(size_t)(k + 2) * HDIM + jj];
    float b3 = V[(size_t)(k + 3) * HDIM + jj];
    #pragma unroll
    for (int rr = 0; rr < 8; ++rr) {
      float4 a = *(const float4*)(Arow[rr] + k);
      acc[rr] = fmaf(a.x, b0, acc[rr]);
      acc[rr] = fmaf(a.y, b1, acc[rr]);
      acc[rr] = fmaf(a.z, b2, acc[rr]);
      acc[rr] = fmaf(a.w, b3, acc[rr]);
    }
  }
  #pragma unroll
  for (int rr = 0; rr < 8; ++rr) {
    int i = i0 + q + rr * 4;
    size_t idx = (size_t)i * N3 + n0 + c;
    if (hv_bf16) ((__hip_bfloat16*)hv)[idx] = __float2bfloat16(acc[rr]);
    else         ((float*)hv)[idx] = acc[rr];
  }
}

// S1: acc = Bb[j] + hV[t,b,j] + x@W  (+ s@U for j<1024)
//   j<512 : rs[b,j]   = sigmoid(acc)*s_old[b,j]
//   <1024 : z [b,j-512]  = sigmoid(acc)
//   else  : ps[b,j-1024] = acc
__global__ void step1_kernel(const float* __restrict__ x,
                             const float* __restrict__ s_old,
                             const float* __restrict__ W,
                             const float* __restrict__ Bb,
                             const float* __restrict__ U,
                             const void* __restrict__ hv, int hv_bf16, int t,
                             float* __restrict__ rs,
                             float* __restrict__ z,
                             float* __restrict__ ps) {
  int c  = threadIdx.x & 63;
  int q  = threadIdx.x >> 6;
  int m0 = blockIdx.x * 32;
  int n0 = blockIdx.y * 64;
  int j  = n0 + c;

  float bb = Bb[j];
  float acc[8];
  #pragma unroll
  for (int rr = 0; rr < 8; ++rr) {
    int b = m0 + q + rr * 4;
    size_t idx = ((size_t)t * BATCH + b) * N3 + j;
    float hvv = hv_bf16 ? __bfloat162float(((const __hip_bfloat16*)hv)[idx])
                        : ((const float*)hv)[idx];
    acc[rr] = bb + hvv;
  }
  // x @ W  (K=256)
  for (int k = 0; k < ODIM; k += 4) {
    float w0 = W[(size_t)(k + 0) * N3 + j];
    float w1 = W[(size_t)(k + 1) * N3 + j];
    float w2 = W[(size_t)(k + 2) * N3 + j];
    float w3 = W[(size_t)(k + 3) * N3 + j];
    #pragma unroll
    for (int rr = 0; rr < 8; ++rr) {
      int b = m0 + q + rr * 4;
      float4 a = *(const float4*)(x + (size_t)b * ODIM + k);
      acc[rr] = fmaf(a.x, w0, acc[rr]);
      acc[rr] = fmaf(a.y, w1, acc[rr]);
      acc[rr] = fmaf(a.z, w2, acc[rr]);
      acc[rr] = fmaf(a.w, w3, acc[rr]);
    }
  }
  if (n0 < 1024) {
    // + s @ U[:, j]  (K=512)
    for (int k = 0; k < HDIM; k += 4) {
      float u0 = U[(size_t)(k + 0) * N3 + j];
      float u1 = U[(size_t)(k + 1) * N3 + j];
      float u2 = U[(size_t)(k + 2) * N3 + j];
      float u3 = U[(size_t)(k + 3) * N3 + j];
      #pragma unroll
      for (int rr = 0; rr < 8; ++rr) {
        int b = m0 + q + rr * 4;
        float4 a = *(const float4*)(s_old + (size_t)b * HDIM + k);
        acc[rr] = fmaf(a.x, u0, acc[rr]);
        acc[rr] = fmaf(a.y, u1, acc[rr]);
        acc[rr] = fmaf(a.z, u2, acc[rr]);
        acc[rr] = fmaf(a.w, u3, acc[rr]);
      }
    }
    if (n0 < 512) {
      #pragma unroll
      for (int rr = 0; rr < 8; ++rr) {
        int b = m0 + q + rr * 4;
        float rv = sigmoidf_(acc[rr]);
        rs[(size_t)b * HDIM + j] = rv * s_old[(size_t)b * HDIM + j];
      }
    } else {
      #pragma unroll
      for (int rr = 0; rr < 8; ++rr) {
        int b = m0 + q + rr * 4;
        z[(size_t)b * HDIM + (j - 512)] = sigmoidf_(acc[rr]);
      }
    }
  } else {
    #pragma unroll
    for (int rr = 0; rr < 8; ++rr) {
      int b = m0 + q + rr * 4;
      ps[(size_t)b * HDIM + (j - 1024)] = acc[rr];
    }
  }
}

// S2: s_new = s + z*(tanh(ps + rs@U_s) - s)
__global__ void step2_kernel(const float* __restrict__ rs,
                             const float* __restrict__ U,
                             const float* __restrict__ ps,
                             const float* __restrict__ z,
                             const float* __restrict__ s_old,
                             float* __restrict__ s_new) {
  int c  = threadIdx.x & 63;
  int q  = threadIdx.x >> 6;
  int m0 = blockIdx.x * 32;
  int n0 = blockIdx.y * 64;
  int h  = n0 + c;

  float acc[8];
  #pragma unroll
  for (int rr = 0; rr < 8; ++rr) acc[rr] = 0.0f;

  for (int k = 0; k < HDIM; k += 4) {
    float u0 = U[(size_t)(k + 0) * N3 + 1024 + h];
    float u1 = U[(size_t)(k + 1) * N3 + 1024 + h];
    float u2 = U[(size_t)(k + 2) * N3 + 1024 + h];
    float u3 = U[(size_t)(k + 3) * N3 + 1024 + h];
    #pragma unroll
    for (int rr = 0; rr < 8; ++rr) {
      int b = m0 + q + rr * 4;
      float4 a = *(const float4*)(rs + (size_t)b * HDIM + k);
      acc[rr] = fmaf(a.x, u0, acc[rr]);
      acc[rr] = fmaf(a.y, u1, acc[rr]);
      acc[rr] = fmaf(a.z, u2, acc[rr]);
      acc[rr] = fmaf(a.w, u3, acc[rr]);
    }
  }
  #pragma unroll
  for (int rr = 0; rr < 8; ++rr) {
    int b = m0 + q + rr * 4;
    size_t idx = (size_t)b * HDIM + h;
    float s1 = tanhf(ps[idx] + acc[rr]);
    float sv = s_old[idx];
    s_new[idx] = sv + z[idx] * (s1 - sv);
  }
}

// S3: x_new = tanh(s_new @ Wxo + b_x); write x state and out[b, t, :]
__global__ void step3_kernel(const float* __restrict__ s_new,
                             const float* __restrict__ W_x,
                             const float* __restrict__ b_x,
                             float* __restrict__ x,
                             float* __restrict__ out, int t) {
  int c  = threadIdx.x & 63;
  int q  = threadIdx.x >> 6;
  int m0 = blockIdx.x * 32;
  int n0 = blockIdx.y * 64;
  int j  = n0 + c;   // 0..255

  float acc[8];
  #pragma unroll
  for (int rr = 0; rr < 8; ++rr) acc[rr] = 0.0f;

  for (int k = 0; k < HDIM; k += 4) {
    float w0 = W_x[(size_t)(k + 0) * 768 + j];
    float w1 = W_x[(size_t)(k + 1) * 768 + j];
    float w2 = W_x[(size_t)(k + 2) * 768 + j];
    float w3 = W_x[(size_t)(k + 3) * 768 + j];
    #pragma unroll
    for (int rr = 0; rr < 8; ++rr) {
      int b = m0 + q + rr * 4;
      float4 a = *(const float4*)(s_new + (size_t)b * HDIM + k);
      acc[rr] = fmaf(a.x, w0, acc[rr]);
      acc[rr] = fmaf(a.y, w1, acc[rr]);
      acc[rr] = fmaf(a.z, w2, acc[rr]);
      acc[rr] = fmaf(a.w, w3, acc[rr]);
    }
  }
  float bx = b_x[j];
  #pragma unroll
  for (int rr = 0; rr < 8; ++rr) {
    int b = m0 + q + rr * 4;
    float xv = tanhf(acc[rr] + bx);
    x[(size_t)b * ODIM + j] = xv;
    out[((size_t)b * TSTEPS + t) * ODIM + j] = xv;
  }
}

extern "C" void kernel_launch(void* const* d_in, const int* in_sizes, int n_in,
                              void* d_out, int out_size, void* d_ws, size_t ws_size,
                              hipStream_t stream) {
  const float* H   = (const float*)d_in[0];
  const float* W   = (const float*)d_in[1];
  const float* Bb  = (const float*)d_in[2];
  const float* U   = (const float*)d_in[3];
  const float* W_x = (const float*)d_in[4];
  const float* b_x = (const float*)d_in[5];
  const float* Vr  = (const float*)d_in[6];
  const float* Vz  = (const float*)d_in[7];
  const float* Vs  = (const float*)d_in[8];
  float* out = (float*)d_out;

  float* wsf = (float*)d_ws;
  float* sA = wsf;
  float* sB = wsf + OFF_SB;
  float* x  = wsf + OFF_X;
  float* z  = wsf + OFF_Z;
  float* rs = wsf + OFF_RS;
  float* ps = wsf + OFF_PS;
  void*  hv = (void*)(wsf + OFF_HV);

  size_t state_bytes  = (size_t)OFF_HV * 4;
  size_t hv_f32_bytes = (size_t)TSTEPS * BATCH * N3 * 4;
  int hv_bf16 = (ws_size < state_bytes + hv_f32_bytes) ? 1 : 0;

  init_kernel<<<256, 256, 0, stream>>>(H, x, sA);
  hv_kernel<<<dim3(2048, 24), 256, 0, stream>>>(H, Vr, Vz, Vs, hv, hv_bf16);

  for (int t = 0; t < TSTEPS; ++t) {
    const float* s_old = (t & 1) ? sB : sA;
    float*       s_new = (t & 1) ? sA : sB;
    step1_kernel<<<dim3(4, 24), 256, 0, stream>>>(x, s_old, W, Bb, U, hv, hv_bf16, t, rs, z, ps);
    step2_kernel<<<dim3(4, 8), 256, 0, stream>>>(rs, U, ps, z, s_old, s_new);
    step3_kernel<<<dim3(4, 4), 256, 0, stream>>>(s_new, W_x, b_x, x, out, t);
  }
}

// Round 2
// 86021.100 us; speedup vs baseline: 1.2175x; 1.2175x over previous
//
#include <hip/hip_runtime.h>
#include <hip/hip_bf16.h>

#define TSTEPS 512
#define BATCH  128
#define DIM    512
#define HDIM   512
#define ODIM   256
#define N3     1536

// ---- ws layout (float offsets) ----
#define OFF_BAR  0         // 512 uints (barrier)
#define OFF_XT   512       // xT  [256][128]
#define OFF_ST   33280     // sT  [512][128]
#define OFF_ZT   98816     // zT  [512][128]
#define OFF_RST  164352    // rsT [512][128]
#define OFF_PST  229888    // psT [512][128]
#define OFF_SUT  295424    // suT [1024][128]
#define OFF_WT   426496    // Wt   [1536][256]
#define OFF_UT1  819712    // Ut1  [1024][512]
#define OFF_UST  1344000   // Ust  [512][512]
#define OFF_WXOT 1606144   // Wxot [256][512]
#define OFF_HV   1737216   // bf16 [512][1536][128]

#define BAR_ROOT  256
#define BAR_EPOCH 272

__device__ __forceinline__ float sigmoid_(float a) {
  return 1.0f / (1.0f + __expf(-a));
}
__device__ __forceinline__ float tanh_(float a) {
  a = fminf(fmaxf(a, -30.0f), 30.0f);
  float e = __expf(2.0f * a);
  return (e - 1.0f) / (e + 1.0f);
}

// ---- one-time weight transposes into ws ----
__global__ void prep_kernel(const float* __restrict__ W, const float* __restrict__ U,
                            const float* __restrict__ Wx, float* __restrict__ ws) {
  int i = blockIdx.x * 256 + threadIdx.x;
  if (i < 393216) {                       // Wt[c][k] = W[k][c]
    int c = i >> 8, k = i & 255;
    ws[OFF_WT + i] = W[(size_t)k * N3 + c];
  } else if (i < 917504) {                // Ut1[c][k] = U[k][c], c<1024
    int j = i - 393216; int c = j >> 9, k = j & 511;
    ws[OFF_UT1 + j] = U[(size_t)k * N3 + c];
  } else if (i < 1179648) {               // Ust[c][k] = U[k][1024+c]
    int j = i - 917504; int c = j >> 9, k = j & 511;
    ws[OFF_UST + j] = U[(size_t)k * N3 + 1024 + c];
  } else if (i < 1310720) {               // Wxot[c][k] = W_x[k][c], c<256
    int j = i - 1179648; int c = j >> 9, k = j & 511;
    ws[OFF_WXOT + j] = Wx[(size_t)k * 768 + c];
  }
}

// ---- state init: s=0, su=0, barrier=0, xT[c][b] = H[b,511,c]+H[b,511,c+256] ----
__global__ void init_kernel(const float* __restrict__ H, float* __restrict__ ws) {
  int i = blockIdx.x * 256 + threadIdx.x;   // grid 512 -> 131072
  if (i < 512) ((unsigned*)ws)[OFF_BAR + i] = 0u;
  if (i < 65536) ws[OFF_ST + i] = 0.0f;
  if (i < 131072) ws[OFF_SUT + i] = 0.0f;
  if (i < 32768) {
    int c = i >> 7, b = i & 127;
    const float* hrow = H + ((size_t)b * TSTEPS + (TSTEPS - 1)) * DIM;
    ws[OFF_XT + i] = hrow[c] + hrow[c + ODIM];
  }
}

// ---- hv precompute, transposed bf16 store: hvT[t][c][b] ----
__global__ void hv_kernel(const float* __restrict__ H,
                          const float* __restrict__ Vr,
                          const float* __restrict__ Vz,
                          const float* __restrict__ Vs,
                          __hip_bfloat16* __restrict__ hvT) {
  __shared__ float tile[64 * 33];
  int c  = threadIdx.x & 63;
  int q  = threadIdx.x >> 6;
  int i0 = blockIdx.x * 32;          // i = l*128 + b (never crosses l boundary)
  int l  = i0 >> 7;
  int b0 = i0 & 127;
  int n0 = blockIdx.y * 64;
  int seg = n0 >> 9;
  int jj  = (n0 & 511) + c;
  const float* V = (seg == 0) ? Vr : ((seg == 1) ? Vz : Vs);

  const float* Arow[8];
  #pragma unroll
  for (int rr = 0; rr < 8; ++rr) {
    int b = b0 + q + rr * 4;
    Arow[rr] = H + ((size_t)b * TSTEPS + (TSTEPS - 1 - l)) * DIM;
  }
  float acc[8];
  #pragma unroll
  for (int rr = 0; rr < 8; ++rr) acc[rr] = 0.0f;

  for (int k = 0; k < DIM; k += 4) {
    float v0 = V[(size_t)(k + 0) * HDIM + jj];
    float v1 = V[(size_t)(k + 1) * HDIM + jj];
    float v2 = V[(size_t)(k + 2) * HDIM + jj];
    float v3 = V[(size_t)(k + 3) * HDIM + jj];
    #pragma unroll
    for (int rr = 0; rr < 8; ++rr) {
      float4 a = *(const float4*)(Arow[rr] + k);
      acc[rr] = fmaf(a.x, v0, acc[rr]);
      acc[rr] = fmaf(a.y, v1, acc[rr]);
      acc[rr] = fmaf(a.z, v2, acc[rr]);
      acc[rr] = fmaf(a.w, v3, acc[rr]);
    }
  }
  #pragma unroll
  for (int rr = 0; rr < 8; ++rr) tile[c * 33 + q + 4 * rr] = acc[rr];
  __syncthreads();
  #pragma unroll
  for (int i = 0; i < 8; ++i) {
    int lin = i * 256 + threadIdx.x;   // 0..2047
    int cc = lin >> 5, bb = lin & 31;
    hvT[((size_t)l * N3 + n0 + cc) * 128 + b0 + bb] = __float2bfloat16(tile[cc * 33 + bb]);
  }
}

// ---- two-level grid barrier (16 groups of 16 blocks) ----
__device__ __forceinline__ void grid_barrier(unsigned* bar, unsigned ep) {
  __syncthreads();
  if (threadIdx.x == 0) {
    __threadfence();   // release this block's writes (agent scope)
    unsigned gslot = (blockIdx.x >> 4) * 16;
    bool released = false;
    if (__hip_atomic_fetch_add(&bar[gslot], 1u, __ATOMIC_ACQ_REL, __HIP_MEMORY_SCOPE_AGENT) == 15u) {
      __hip_atomic_store(&bar[gslot], 0u, __ATOMIC_RELAXED, __HIP_MEMORY_SCOPE_AGENT);
      if (__hip_atomic_fetch_add(&bar[BAR_ROOT], 1u, __ATOMIC_ACQ_REL, __HIP_MEMORY_SCOPE_AGENT) == 15u) {
        __hip_atomic_store(&bar[BAR_ROOT], 0u, __ATOMIC_RELAXED, __HIP_MEMORY_SCOPE_AGENT);
        __hip_atomic_store(&bar[BAR_EPOCH], ep, __ATOMIC_RELEASE, __HIP_MEMORY_SCOPE_AGENT);
        released = true;
      }
    }
    if (!released) {
      while (__hip_atomic_load(&bar[BAR_EPOCH], __ATOMIC_ACQUIRE, __HIP_MEMORY_SCOPE_AGENT) < ep) {}
    }
    __threadfence();   // acquire side
  }
  __syncthreads();
}

// ---- persistent scan: 256 blocks x 256 threads ----
__global__ __launch_bounds__(256) void scan_kernel(
    const float* __restrict__ Bb, const float* __restrict__ b_x,
    float* __restrict__ ws, float* __restrict__ out)
{
  float* xT  = ws + OFF_XT;
  float* sT  = ws + OFF_ST;
  float* zT  = ws + OFF_ZT;
  float* rsT = ws + OFF_RST;
  float* psT = ws + OFF_PST;
  float* suT = ws + OFF_SUT;
  const float* Wt   = ws + OFF_WT;
  const float* Ut1  = ws + OFF_UT1;
  const float* Ust  = ws + OFF_UST;
  const float* Wxot = ws + OFF_WXOT;
  const __hip_bfloat16* hvT = (const __hip_bfloat16*)(ws + OFF_HV);
  unsigned* bar = (unsigned*)ws;

  const int tid = threadIdx.x;
  const int bid = blockIdx.x;
  const int cg  = bid >> 2;          // 0..63
  const int r0  = (bid & 3) * 32;
  const int row = tid & 31;
  const int b   = r0 + row;          // batch row
  const int g   = tid >> 5;          // 0..7

  const int c1 = cg * 24 + g * 3;    // phase1: 3 cols
  const int h2 = cg * 8 + g;         // phase2: 1 col
  const int c3 = cg * 16 + g * 2;    // phase3: 2 su cols
  const int xc = cg * 4 + (g & 3);   // phase3: 1 x col (g<4)
  const bool do_x = (g < 4);

  unsigned ep = 0;

  // hv prefetch registers (t=0)
  float hv0 = __bfloat162float(hvT[((size_t)0 * N3 + c1 + 0) * 128 + b]);
  float hv1 = __bfloat162float(hvT[((size_t)0 * N3 + c1 + 1) * 128 + b]);
  float hv2 = __bfloat162float(hvT[((size_t)0 * N3 + c1 + 2) * 128 + b]);

  for (int t = 0; t < TSTEPS; ++t) {
    // ================= Phase 1: gates =================
    {
      const float4* B0 = (const float4*)(Wt + (size_t)(c1 + 0) * 256);
      const float4* B1 = (const float4*)(Wt + (size_t)(c1 + 1) * 256);
      const float4* B2 = (const float4*)(Wt + (size_t)(c1 + 2) * 256);
      float a0 = 0.0f, a1 = 0.0f, a2 = 0.0f;
      #pragma unroll 4
      for (int k4 = 0; k4 < 64; ++k4) {
        float4 w0 = B0[k4], w1 = B1[k4], w2 = B2[k4];
        int k = k4 * 4;
        float x0 = xT[(k + 0) * 128 + b];
        float x1 = xT[(k + 1) * 128 + b];
        float x2 = xT[(k + 2) * 128 + b];
        float x3 = xT[(k + 3) * 128 + b];
        a0 = fmaf(x0, w0.x, a0); a0 = fmaf(x1, w0.y, a0); a0 = fmaf(x2, w0.z, a0); a0 = fmaf(x3, w0.w, a0);
        a1 = fmaf(x0, w1.x, a1); a1 = fmaf(x1, w1.y, a1); a1 = fmaf(x2, w1.z, a1); a1 = fmaf(x3, w1.w, a1);
        a2 = fmaf(x0, w2.x, a2); a2 = fmaf(x1, w2.y, a2); a2 = fmaf(x2, w2.z, a2); a2 = fmaf(x3, w2.w, a2);
      }
      float accs[3] = {a0 + hv0, a1 + hv1, a2 + hv2};
      #pragma unroll
      for (int i = 0; i < 3; ++i) {
        int c = c1 + i;
        float pre = accs[i] + Bb[c] + ((c < 1024) ? suT[(size_t)c * 128 + b] : 0.0f);
        if (c < 512)        rsT[c * 128 + b] = sigmoid_(pre) * sT[c * 128 + b];
        else if (c < 1024)  zT[(c - 512) * 128 + b] = sigmoid_(pre);
        else                psT[(c - 1024) * 128 + b] = pre;
      }
    }
    grid_barrier(bar, ++ep);

    // ================= Phase 2: state update =================
    {
      if (t + 1 < TSTEPS) {   // prefetch next hv slice (read-only, safe anytime)
        hv0 = __bfloat162float(hvT[((size_t)(t + 1) * N3 + c1 + 0) * 128 + b]);
        hv1 = __bfloat162float(hvT[((size_t)(t + 1) * N3 + c1 + 1) * 128 + b]);
        hv2 = __bfloat162float(hvT[((size_t)(t + 1) * N3 + c1 + 2) * 128 + b]);
      }
      const float4* Bu = (const float4*)(Ust + (size_t)h2 * 512);
      float acc = 0.0f;
      #pragma unroll 4
      for (int k4 = 0; k4 < 128; ++k4) {
        float4 w = Bu[k4];
        int k = k4 * 4;
        acc = fmaf(rsT[(k + 0) * 128 + b], w.x, acc);
        acc = fmaf(rsT[(k + 1) * 128 + b], w.y, acc);
        acc = fmaf(rsT[(k + 2) * 128 + b], w.z, acc);
        acc = fmaf(rsT[(k + 3) * 128 + b], w.w, acc);
      }
      int idx = h2 * 128 + b;
      float s1 = tanh_(psT[idx] + acc);
      float sv = sT[idx];
      sT[idx] = sv + zT[idx] * (s1 - sv);
    }
    grid_barrier(bar, ++ep);

    // ================= Phase 3: x_out + su lookahead =================
    {
      const float4* Bu0 = (const float4*)(Ut1 + (size_t)(c3 + 0) * 512);
      const float4* Bu1 = (const float4*)(Ut1 + (size_t)(c3 + 1) * 512);
      const float4* Bx  = (const float4*)(Wxot + (size_t)xc * 512);
      float a0 = 0.0f, a1 = 0.0f, ax = 0.0f;
      #pragma unroll 4
      for (int k4 = 0; k4 < 128; ++k4) {
        float4 w0 = Bu0[k4], w1 = Bu1[k4];
        int k = k4 * 4;
        float s0v = sT[(k + 0) * 128 + b];
        float s1v = sT[(k + 1) * 128 + b];
        float s2v = sT[(k + 2) * 128 + b];
        float s3v = sT[(k + 3) * 128 + b];
        a0 = fmaf(s0v, w0.x, a0); a0 = fmaf(s1v, w0.y, a0); a0 = fmaf(s2v, w0.z, a0); a0 = fmaf(s3v, w0.w, a0);
        a1 = fmaf(s0v, w1.x, a1); a1 = fmaf(s1v, w1.y, a1); a1 = fmaf(s2v, w1.z, a1); a1 = fmaf(s3v, w1.w, a1);
        if (do_x) {
          float4 wx = Bx[k4];
          ax = fmaf(s0v, wx.x, ax); ax = fmaf(s1v, wx.y, ax); ax = fmaf(s2v, wx.z, ax); ax = fmaf(s3v, wx.w, ax);
        }
      }
      suT[(size_t)(c3 + 0) * 128 + b] = a0;
      suT[(size_t)(c3 + 1) * 128 + b] = a1;
      if (do_x) {
        float xv = tanh_(ax + b_x[xc]);
        xT[xc * 128 + b] = xv;
        out[((size_t)b * TSTEPS + t) * ODIM + xc] = xv;
      }
    }
    grid_barrier(bar, ++ep);
  }
}

extern "C" void kernel_launch(void* const* d_in, const int* in_sizes, int n_in,
                              void* d_out, int out_size, void* d_ws, size_t ws_size,
                              hipStream_t stream) {
  const float* H   = (const float*)d_in[0];
  const float* W   = (const float*)d_in[1];
  const float* Bb  = (const float*)d_in[2];
  const float* U   = (const float*)d_in[3];
  const float* W_x = (const float*)d_in[4];
  const float* b_x = (const float*)d_in[5];
  const float* Vr  = (const float*)d_in[6];
  const float* Vz  = (const float*)d_in[7];
  const float* Vs  = (const float*)d_in[8];
  float* out = (float*)d_out;
  float* ws  = (float*)d_ws;
  __hip_bfloat16* hvT = (__hip_bfloat16*)(ws + OFF_HV);

  prep_kernel<<<5120, 256, 0, stream>>>(W, U, W_x, ws);
  init_kernel<<<512, 256, 0, stream>>>(H, ws);
  hv_kernel<<<dim3(2048, 24), 256, 0, stream>>>(H, Vr, Vz, Vs, hvT);
  scan_kernel<<<256, 256, 0, stream>>>(Bb, b_x, ws, out);
}

// Round 3
// 42101.773 us; speedup vs baseline: 2.4875x; 2.0432x over previous
//
#include <hip/hip_runtime.h>
#include <hip/hip_bf16.h>

#define TSTEPS 512
#define BATCH  128
#define DIM    512
#define HDIM   512
#define ODIM   256
#define N3     1536

// ---- ws layout (float offsets) ----
#define OFF_BAR  0         // 512 uints (barrier)
#define OFF_XT   512       // xT  [256][128]
#define OFF_ST   33280     // sT  [512][128]
#define OFF_ZT   98816     // zT  [512][128]
#define OFF_RST  164352    // rsT [512][128]
#define OFF_PST  229888    // psT [512][128]
#define OFF_SUT  295424    // suT [1024][128]
#define OFF_WT   426496    // Wt   [1536][256]
#define OFF_UT1  819712    // Ut1  [1024][512]
#define OFF_UST  1344000   // Ust  [512][512]
#define OFF_WXOT 1606144   // Wxot [256][512]
#define OFF_HV   1737216   // bf16 [512][1536][128]

#define BAR_ROOT  256
#define BAR_EPOCH 272

__device__ __forceinline__ float sigmoid_(float a) {
  return 1.0f / (1.0f + __expf(-a));
}
__device__ __forceinline__ float tanh_(float a) {
  a = fminf(fmaxf(a, -30.0f), 30.0f);
  float e = __expf(2.0f * a);
  return (e - 1.0f) / (e + 1.0f);
}

// LLC-coherent state accessors (sc1 encoding, bypass incoherent per-XCD L2,
// NO fence instructions — weights stay cached in L1/L2).
__device__ __forceinline__ float ld(const float* p) {
  return __hip_atomic_load((float*)p, __ATOMIC_RELAXED, __HIP_MEMORY_SCOPE_AGENT);
}
__device__ __forceinline__ void st(float* p, float v) {
  __hip_atomic_store(p, v, __ATOMIC_RELAXED, __HIP_MEMORY_SCOPE_AGENT);
}

// ---- one-time weight transposes into ws ----
__global__ void prep_kernel(const float* __restrict__ W, const float* __restrict__ U,
                            const float* __restrict__ Wx, float* __restrict__ ws) {
  int i = blockIdx.x * 256 + threadIdx.x;
  if (i < 393216) {                       // Wt[c][k] = W[k][c]
    int c = i >> 8, k = i & 255;
    ws[OFF_WT + i] = W[(size_t)k * N3 + c];
  } else if (i < 917504) {                // Ut1[c][k] = U[k][c], c<1024
    int j = i - 393216; int c = j >> 9, k = j & 511;
    ws[OFF_UT1 + j] = U[(size_t)k * N3 + c];
  } else if (i < 1179648) {               // Ust[c][k] = U[k][1024+c]
    int j = i - 917504; int c = j >> 9, k = j & 511;
    ws[OFF_UST + j] = U[(size_t)k * N3 + 1024 + c];
  } else if (i < 1310720) {               // Wxot[c][k] = W_x[k][c], c<256
    int j = i - 1179648; int c = j >> 9, k = j & 511;
    ws[OFF_WXOT + j] = Wx[(size_t)k * 768 + c];
  }
}

// ---- state init ----
__global__ void init_kernel(const float* __restrict__ H, float* __restrict__ ws) {
  int i = blockIdx.x * 256 + threadIdx.x;   // grid 512 -> 131072
  if (i < 512) ((unsigned*)ws)[OFF_BAR + i] = 0u;
  if (i < 65536) ws[OFF_ST + i] = 0.0f;
  if (i < 131072) ws[OFF_SUT + i] = 0.0f;
  if (i < 32768) {
    int c = i >> 7, b = i & 127;
    const float* hrow = H + ((size_t)b * TSTEPS + (TSTEPS - 1)) * DIM;
    ws[OFF_XT + i] = hrow[c] + hrow[c + ODIM];
  }
}

// ---- hv precompute, transposed bf16 store: hvT[t][c][b] ----
__global__ void hv_kernel(const float* __restrict__ H,
                          const float* __restrict__ Vr,
                          const float* __restrict__ Vz,
                          const float* __restrict__ Vs,
                          __hip_bfloat16* __restrict__ hvT) {
  __shared__ float tile[64 * 33];
  int c  = threadIdx.x & 63;
  int q  = threadIdx.x >> 6;
  int i0 = blockIdx.x * 32;
  int l  = i0 >> 7;
  int b0 = i0 & 127;
  int n0 = blockIdx.y * 64;
  int seg = n0 >> 9;
  int jj  = (n0 & 511) + c;
  const float* V = (seg == 0) ? Vr : ((seg == 1) ? Vz : Vs);

  const float* Arow[8];
  #pragma unroll
  for (int rr = 0; rr < 8; ++rr) {
    int b = b0 + q + rr * 4;
    Arow[rr] = H + ((size_t)b * TSTEPS + (TSTEPS - 1 - l)) * DIM;
  }
  float acc[8];
  #pragma unroll
  for (int rr = 0; rr < 8; ++rr) acc[rr] = 0.0f;

  for (int k = 0; k < DIM; k += 4) {
    float v0 = V[(size_t)(k + 0) * HDIM + jj];
    float v1 = V[(size_t)(k + 1) * HDIM + jj];
    float v2 = V[(size_t)(k + 2) * HDIM + jj];
    float v3 = V[(size_t)(k + 3) * HDIM + jj];
    #pragma unroll
    for (int rr = 0; rr < 8; ++rr) {
      float4 a = *(const float4*)(Arow[rr] + k);
      acc[rr] = fmaf(a.x, v0, acc[rr]);
      acc[rr] = fmaf(a.y, v1, acc[rr]);
      acc[rr] = fmaf(a.z, v2, acc[rr]);
      acc[rr] = fmaf(a.w, v3, acc[rr]);
    }
  }
  #pragma unroll
  for (int rr = 0; rr < 8; ++rr) tile[c * 33 + q + 4 * rr] = acc[rr];
  __syncthreads();
  #pragma unroll
  for (int i = 0; i < 8; ++i) {
    int lin = i * 256 + threadIdx.x;
    int cc = lin >> 5, bb = lin & 31;
    hvT[((size_t)l * N3 + n0 + cc) * 128 + b0 + bb] = __float2bfloat16(tile[cc * 33 + bb]);
  }
}

// ---- fence-free grid barrier: monotonic counters, relaxed agent atomics ----
__device__ __forceinline__ void grid_barrier(unsigned* bar, unsigned ep) {
  __syncthreads();   // drains block's vmem (compiler emits waitcnt before s_barrier)
  if (threadIdx.x == 0) {
    asm volatile("s_waitcnt vmcnt(0)" ::: "memory");
    unsigned gslot = (blockIdx.x >> 4) * 16;     // 16 groups x 16 blocks, 64B apart
    unsigned tgt = ep * 16u;
    if (__hip_atomic_fetch_add(&bar[gslot], 1u, __ATOMIC_RELAXED, __HIP_MEMORY_SCOPE_AGENT) == tgt - 1u) {
      if (__hip_atomic_fetch_add(&bar[BAR_ROOT], 1u, __ATOMIC_RELAXED, __HIP_MEMORY_SCOPE_AGENT) == tgt - 1u) {
        __hip_atomic_store(&bar[BAR_EPOCH], ep, __ATOMIC_RELAXED, __HIP_MEMORY_SCOPE_AGENT);
      } else {
        while (__hip_atomic_load(&bar[BAR_EPOCH], __ATOMIC_RELAXED, __HIP_MEMORY_SCOPE_AGENT) < ep) {}
      }
    } else {
      while (__hip_atomic_load(&bar[BAR_EPOCH], __ATOMIC_RELAXED, __HIP_MEMORY_SCOPE_AGENT) < ep) {}
    }
  }
  __syncthreads();
}

// ---- persistent scan: 256 blocks x 256 threads ----
__global__ __launch_bounds__(256) void scan_kernel(
    const float* __restrict__ Bb, const float* __restrict__ b_x,
    float* __restrict__ ws, float* __restrict__ out)
{
  float* xT  = ws + OFF_XT;
  float* sT  = ws + OFF_ST;
  float* zT  = ws + OFF_ZT;
  float* rsT = ws + OFF_RST;
  float* psT = ws + OFF_PST;
  float* suT = ws + OFF_SUT;
  const float* Wt   = ws + OFF_WT;
  const float* Ut1  = ws + OFF_UT1;
  const float* Ust  = ws + OFF_UST;
  const float* Wxot = ws + OFF_WXOT;
  const __hip_bfloat16* hvT = (const __hip_bfloat16*)(ws + OFF_HV);
  unsigned* bar = (unsigned*)ws;

  const int tid = threadIdx.x;
  const int bid = blockIdx.x;
  const int cg  = bid >> 2;          // 0..63
  const int r0  = (bid & 3) * 32;
  const int row = tid & 31;
  const int b   = r0 + row;          // batch row
  const int g   = tid >> 5;          // 0..7

  const int c1 = cg * 24 + g * 3;    // phase1: 3 cols
  const int h2 = cg * 8 + g;         // phase2: 1 col
  const int c3 = cg * 16 + g * 2;    // phase3: 2 su cols
  const int xc = cg * 4 + (g & 3);   // phase3: 1 x col (g<4)
  const bool do_x = (g < 4);

  unsigned ep = 0;

  float hv0 = __bfloat162float(hvT[((size_t)0 * N3 + c1 + 0) * 128 + b]);
  float hv1 = __bfloat162float(hvT[((size_t)0 * N3 + c1 + 1) * 128 + b]);
  float hv2 = __bfloat162float(hvT[((size_t)0 * N3 + c1 + 2) * 128 + b]);

  for (int t = 0; t < TSTEPS; ++t) {
    // ================= Phase 1: gates =================
    {
      const float4* B0 = (const float4*)(Wt + (size_t)(c1 + 0) * 256);
      const float4* B1 = (const float4*)(Wt + (size_t)(c1 + 1) * 256);
      const float4* B2 = (const float4*)(Wt + (size_t)(c1 + 2) * 256);
      float a0 = 0.0f, a1 = 0.0f, a2 = 0.0f;
      #pragma unroll 4
      for (int k4 = 0; k4 < 64; ++k4) {
        float4 w0 = B0[k4], w1 = B1[k4], w2 = B2[k4];
        int k = k4 * 4;
        float x0 = ld(xT + (k + 0) * 128 + b);
        float x1 = ld(xT + (k + 1) * 128 + b);
        float x2 = ld(xT + (k + 2) * 128 + b);
        float x3 = ld(xT + (k + 3) * 128 + b);
        a0 = fmaf(x0, w0.x, a0); a0 = fmaf(x1, w0.y, a0); a0 = fmaf(x2, w0.z, a0); a0 = fmaf(x3, w0.w, a0);
        a1 = fmaf(x0, w1.x, a1); a1 = fmaf(x1, w1.y, a1); a1 = fmaf(x2, w1.z, a1); a1 = fmaf(x3, w1.w, a1);
        a2 = fmaf(x0, w2.x, a2); a2 = fmaf(x1, w2.y, a2); a2 = fmaf(x2, w2.z, a2); a2 = fmaf(x3, w2.w, a2);
      }
      float accs[3] = {a0 + hv0, a1 + hv1, a2 + hv2};
      #pragma unroll
      for (int i = 0; i < 3; ++i) {
        int c = c1 + i;
        float pre = accs[i] + Bb[c] + ((c < 1024) ? ld(suT + (size_t)c * 128 + b) : 0.0f);
        if (c < 512)        st(rsT + c * 128 + b, sigmoid_(pre) * ld(sT + c * 128 + b));
        else if (c < 1024)  st(zT + (c - 512) * 128 + b, sigmoid_(pre));
        else                st(psT + (c - 1024) * 128 + b, pre);
      }
    }
    grid_barrier(bar, ++ep);

    // ================= Phase 2: state update =================
    {
      if (t + 1 < TSTEPS) {
        hv0 = __bfloat162float(hvT[((size_t)(t + 1) * N3 + c1 + 0) * 128 + b]);
        hv1 = __bfloat162float(hvT[((size_t)(t + 1) * N3 + c1 + 1) * 128 + b]);
        hv2 = __bfloat162float(hvT[((size_t)(t + 1) * N3 + c1 + 2) * 128 + b]);
      }
      const float4* Bu = (const float4*)(Ust + (size_t)h2 * 512);
      float acc = 0.0f;
      #pragma unroll 4
      for (int k4 = 0; k4 < 128; ++k4) {
        float4 w = Bu[k4];
        int k = k4 * 4;
        acc = fmaf(ld(rsT + (k + 0) * 128 + b), w.x, acc);
        acc = fmaf(ld(rsT + (k + 1) * 128 + b), w.y, acc);
        acc = fmaf(ld(rsT + (k + 2) * 128 + b), w.z, acc);
        acc = fmaf(ld(rsT + (k + 3) * 128 + b), w.w, acc);
      }
      int idx = h2 * 128 + b;
      float s1 = tanh_(ld(psT + idx) + acc);
      float sv = ld(sT + idx);
      st(sT + idx, sv + ld(zT + idx) * (s1 - sv));
    }
    grid_barrier(bar, ++ep);

    // ================= Phase 3: x_out + su lookahead =================
    {
      const float4* Bu0 = (const float4*)(Ut1 + (size_t)(c3 + 0) * 512);
      const float4* Bu1 = (const float4*)(Ut1 + (size_t)(c3 + 1) * 512);
      const float4* Bx  = (const float4*)(Wxot + (size_t)xc * 512);
      float a0 = 0.0f, a1 = 0.0f, ax = 0.0f;
      #pragma unroll 4
      for (int k4 = 0; k4 < 128; ++k4) {
        float4 w0 = Bu0[k4], w1 = Bu1[k4];
        int k = k4 * 4;
        float s0v = ld(sT + (k + 0) * 128 + b);
        float s1v = ld(sT + (k + 1) * 128 + b);
        float s2v = ld(sT + (k + 2) * 128 + b);
        float s3v = ld(sT + (k + 3) * 128 + b);
        a0 = fmaf(s0v, w0.x, a0); a0 = fmaf(s1v, w0.y, a0); a0 = fmaf(s2v, w0.z, a0); a0 = fmaf(s3v, w0.w, a0);
        a1 = fmaf(s0v, w1.x, a1); a1 = fmaf(s1v, w1.y, a1); a1 = fmaf(s2v, w1.z, a1); a1 = fmaf(s3v, w1.w, a1);
        if (do_x) {
          float4 wx = Bx[k4];
          ax = fmaf(s0v, wx.x, ax); ax = fmaf(s1v, wx.y, ax); ax = fmaf(s2v, wx.z, ax); ax = fmaf(s3v, wx.w, ax);
        }
      }
      st(suT + (size_t)(c3 + 0) * 128 + b, a0);
      st(suT + (size_t)(c3 + 1) * 128 + b, a1);
      if (do_x) {
        float xv = tanh_(ax + b_x[xc]);
        st(xT + xc * 128 + b, xv);
        out[((size_t)b * TSTEPS + t) * ODIM + xc] = xv;
      }
    }
    grid_barrier(bar, ++ep);
  }
}

extern "C" void kernel_launch(void* const* d_in, const int* in_sizes, int n_in,
                              void* d_out, int out_size, void* d_ws, size_t ws_size,
                              hipStream_t stream) {
  const float* H   = (const float*)d_in[0];
  const float* W   = (const float*)d_in[1];
  const float* Bb  = (const float*)d_in[2];
  const float* U   = (const float*)d_in[3];
  const float* W_x = (const float*)d_in[4];
  const float* b_x = (const float*)d_in[5];
  const float* Vr  = (const float*)d_in[6];
  const float* Vz  = (const float*)d_in[7];
  const float* Vs  = (const float*)d_in[8];
  float* out = (float*)d_out;
  float* ws  = (float*)d_ws;
  __hip_bfloat16* hvT = (__hip_bfloat16*)(ws + OFF_HV);

  prep_kernel<<<5120, 256, 0, stream>>>(W, U, W_x, ws);
  init_kernel<<<512, 256, 0, stream>>>(H, ws);
  hv_kernel<<<dim3(2048, 24), 256, 0, stream>>>(H, Vr, Vz, Vs, hvT);
  scan_kernel<<<256, 256, 0, stream>>>(Bb, b_x, ws, out);
}